// Round 2
// baseline (492.644 us; speedup 1.0000x reference)
//
#include <hip/hip_runtime.h>
#include <math.h>

#define NCAND 80
#define NPT 8  // float4 chunks per thread in k_scores (32 elements)

// Hardware transcendentals: v_exp_f32 is 2^x, v_log_f32 is log2(x).
// __has_builtin guards keep the host-compile pass (no AMDGCN builtins) parseable.
#if defined(__HIP_DEVICE_COMPILE__) && __has_builtin(__builtin_amdgcn_exp2f)
#define EXP2F(x) __builtin_amdgcn_exp2f(x)
#else
#define EXP2F(x) exp2f(x)
#endif
#if defined(__HIP_DEVICE_COMPILE__) && __has_builtin(__builtin_amdgcn_logf)
#define LOG2F(x) __builtin_amdgcn_logf(x)
#else
#define LOG2F(x) log2f(x)
#endif

struct WS {
  unsigned int min_ord;     // ordered-uint encoding of running min
  unsigned int max_ord;     // ordered-uint encoding of running max
  unsigned int pad[14];     // align scores to 64B
  double scores[NCAND];     // per-candidate sum of |err|^2.4 (sum, not mean: argmin-equivalent)
  float4 final_params;      // {delta, 1/delta, -zp, 255-zp} for final quant
};

// float <-> order-preserving uint (no NaNs in input)
__device__ __forceinline__ unsigned int f2o(float f) {
  unsigned int u = __float_as_uint(f);
  return (u & 0x80000000u) ? ~u : (u | 0x80000000u);
}
__device__ __forceinline__ float o2f(unsigned int o) {
  unsigned int u = (o & 0x80000000u) ? (o ^ 0x80000000u) : ~o;
  return __uint_as_float(u);
}

__global__ void k_init(WS* ws) {
  int t = threadIdx.x;
  if (t < NCAND) ws->scores[t] = 0.0;
  if (t == 0) { ws->min_ord = 0xFFFFFFFFu; ws->max_ord = 0u; }
}

__global__ __launch_bounds__(256) void k_minmax(const float4* __restrict__ x4, int n4, WS* ws) {
  float mn = INFINITY, mx = -INFINITY;
  int idx = blockIdx.x * blockDim.x + threadIdx.x;
  int stride = gridDim.x * blockDim.x;
  for (int i = idx; i < n4; i += stride) {
    float4 v = x4[i];
    mn = fminf(mn, fminf(fminf(v.x, v.y), fminf(v.z, v.w)));
    mx = fmaxf(mx, fmaxf(fmaxf(v.x, v.y), fmaxf(v.z, v.w)));
  }
  #pragma unroll
  for (int off = 32; off; off >>= 1) {
    mn = fminf(mn, __shfl_xor(mn, off));
    mx = fmaxf(mx, __shfl_xor(mx, off));
  }
  __shared__ float smn[4], smx[4];
  int wid = threadIdx.x >> 6;
  if ((threadIdx.x & 63) == 0) { smn[wid] = mn; smx[wid] = mx; }
  __syncthreads();
  if (threadIdx.x == 0) {
    mn = fminf(fminf(smn[0], smn[1]), fminf(smn[2], smn[3]));
    mx = fmaxf(fmaxf(smx[0], smx[1]), fmaxf(smx[2], smx[3]));
    atomicMin(&ws->min_ord, f2o(mn));
    atomicMax(&ws->max_ord, f2o(mx));
  }
}

// One pass over x: 32 elements per thread held in VGPRs; runtime loop over the
// 80 candidates (constants broadcast from LDS). Sum compared instead of mean
// (N identical across candidates). Padding elements use x=0 -> err==0 -> adds 0.
__global__ __launch_bounds__(256) void k_scores(const float4* __restrict__ x4, int n4, WS* ws) {
  __shared__ float4 cc[NCAND];   // {delta, 1/delta, -zp, 255-zp}
  if (threadIdx.x < NCAND) {
    float xmin = o2f(ws->min_ord);
    float xmax = o2f(ws->max_ord);
    float f  = 1.0f - (float)threadIdx.x * 0.01f;   // matches ref f32 arith
    float mn = xmin * f, mx = xmax * f;
    float delta = fmaxf(mx - mn, 1e-8f) / 255.0f;   // IEEE div, once
    float zp = rintf(-mn / delta);                  // round-half-even == jnp.round
    cc[threadIdx.x] = make_float4(delta, 1.0f / delta, -zp, 255.0f - zp);
  }
  __syncthreads();

  float xv[4 * NPT];
  int base = blockIdx.x * (256 * NPT) + threadIdx.x;  // float4 index, coalesced
  #pragma unroll
  for (int j = 0; j < NPT; j++) {
    int i = base + j * 256;
    float4 v = (i < n4) ? x4[i] : make_float4(0.f, 0.f, 0.f, 0.f);
    xv[4 * j + 0] = v.x; xv[4 * j + 1] = v.y;
    xv[4 * j + 2] = v.z; xv[4 * j + 3] = v.w;
  }

  __shared__ float part[4][NCAND];
  int wid = threadIdx.x >> 6, lane = threadIdx.x & 63;

  #pragma unroll 1  // keep candidates a runtime loop: prevents hoisting 80 float4 LDS loads into VGPRs
  for (int c = 0; c < NCAND; c++) {
    float4 k = cc[c];
    float s0 = 0.f, s1 = 0.f, s2 = 0.f, s3 = 0.f;  // break the dependent add chain
    #pragma unroll
    for (int e = 0; e < 4 * NPT; e += 4) {
      float xa = xv[e], xb = xv[e + 1], xc = xv[e + 2], xd = xv[e + 3];
      float ra = fminf(fmaxf(rintf(xa * k.y), k.z), k.w);  // -> v_med3_f32
      float rb = fminf(fmaxf(rintf(xb * k.y), k.z), k.w);
      float rc = fminf(fmaxf(rintf(xc * k.y), k.z), k.w);
      float rd = fminf(fmaxf(rintf(xd * k.y), k.z), k.w);
      float ea = fabsf(fmaf(ra, k.x, -xa));
      float eb = fabsf(fmaf(rb, k.x, -xb));
      float ec = fabsf(fmaf(rc, k.x, -xc));
      float ed = fabsf(fmaf(rd, k.x, -xd));
      s0 += EXP2F(2.4f * LOG2F(ea));   // |e|^2.4 ; e==0 -> exp2(-inf)=0
      s1 += EXP2F(2.4f * LOG2F(eb));
      s2 += EXP2F(2.4f * LOG2F(ec));
      s3 += EXP2F(2.4f * LOG2F(ed));
    }
    float s = (s0 + s1) + (s2 + s3);
    #pragma unroll
    for (int off = 32; off; off >>= 1) s += __shfl_xor(s, off);
    if (lane == 0) part[wid][c] = s;
  }
  __syncthreads();
  if (threadIdx.x < NCAND) {
    double tot = (double)part[0][threadIdx.x] + (double)part[1][threadIdx.x]
               + (double)part[2][threadIdx.x] + (double)part[3][threadIdx.x];
    atomicAdd(&ws->scores[threadIdx.x], tot);
  }
}

__global__ void k_argmin(WS* ws, const float* __restrict__ minbuf, const float* __restrict__ maxbuf) {
  if (threadIdx.x == 0 && blockIdx.x == 0) {
    double best = ws->scores[0];
    int bi = 0;
    for (int i = 1; i < NCAND; i++) {           // ties -> first (strict <)
      double s = ws->scores[i];
      if (s < best) { best = s; bi = i; }
    }
    float factor = 1.0f - (float)bi * 0.01f;
    float xmin = o2f(ws->min_ord), xmax = o2f(ws->max_ord);
    float save_min = xmin * factor, save_max = xmax * factor;
    // EMA: buf*0.9 + save*0.1 (f32, matching jnp weak-type promotion)
    float new_min = minbuf[0] * 0.9f + save_min * 0.1f;
    float new_max = maxbuf[0] * 0.9f + save_max * 0.1f;
    float delta = fmaxf(new_max - new_min, 1e-8f) / 255.0f;
    float zp = rintf(-new_min / delta);
    ws->final_params = make_float4(delta, 1.0f / delta, -zp, 255.0f - zp);
  }
}

__global__ __launch_bounds__(256) void k_quant(const float4* __restrict__ x4, float4* __restrict__ o4,
                                               int n4, const WS* __restrict__ ws) {
  float4 k = ws->final_params;  // uniform load, L2-broadcast
  int idx = blockIdx.x * blockDim.x + threadIdx.x;
  int stride = gridDim.x * blockDim.x;
  for (int i = idx; i < n4; i += stride) {
    float4 v = x4[i];
    float4 o;
    o.x = fminf(fmaxf(rintf(v.x * k.y), k.z), k.w) * k.x;
    o.y = fminf(fmaxf(rintf(v.y * k.y), k.z), k.w) * k.x;
    o.z = fminf(fmaxf(rintf(v.z * k.y), k.z), k.w) * k.x;
    o.w = fminf(fmaxf(rintf(v.w * k.y), k.z), k.w) * k.x;
    o4[i] = o;
  }
}

extern "C" void kernel_launch(void* const* d_in, const int* in_sizes, int n_in,
                              void* d_out, int out_size, void* d_ws, size_t ws_size,
                              hipStream_t stream) {
  const float* x      = (const float*)d_in[0];
  const float* minbuf = (const float*)d_in[1];
  const float* maxbuf = (const float*)d_in[2];
  float* out = (float*)d_out;
  WS* ws = (WS*)d_ws;
  int n  = in_sizes[0];
  int n4 = n / 4;  // n = 16,777,216 -> divisible

  k_init<<<1, 128, 0, stream>>>(ws);

  int mmBlocks = (n4 + 256 * 8 - 1) / (256 * 8);
  if (mmBlocks > 2048) mmBlocks = 2048;
  k_minmax<<<mmBlocks, 256, 0, stream>>>((const float4*)x, n4, ws);

  int scBlocks = (n4 + 256 * NPT - 1) / (256 * NPT);  // 2048 for n=16M
  k_scores<<<scBlocks, 256, 0, stream>>>((const float4*)x, n4, ws);

  k_argmin<<<1, 64, 0, stream>>>(ws, minbuf, maxbuf);

  int qBlocks = (n4 + 256 * 4 - 1) / (256 * 4);
  if (qBlocks > 4096) qBlocks = 4096;
  k_quant<<<qBlocks, 256, 0, stream>>>((const float4*)x, (float4*)out, n4, ws);
}

// Round 3
// 229.455 us; speedup vs baseline: 2.1470x; 2.1470x over previous
//
#include <hip/hip_runtime.h>
#include <math.h>

#define NCAND 80
#define NEXACT 17          // exact-eval window size (subsample argmin +/- 8)
#define NPT 8              // float4 chunks per thread in k_exact (32 elements)

// Hardware transcendentals: v_exp_f32 is 2^x, v_log_f32 is log2(x).
#if defined(__HIP_DEVICE_COMPILE__) && __has_builtin(__builtin_amdgcn_exp2f)
#define EXP2F(x) __builtin_amdgcn_exp2f(x)
#else
#define EXP2F(x) exp2f(x)
#endif
#if defined(__HIP_DEVICE_COMPILE__) && __has_builtin(__builtin_amdgcn_logf)
#define LOG2F(x) __builtin_amdgcn_logf(x)
#else
#define LOG2F(x) log2f(x)
#endif

struct WS {
  unsigned int min_ord;          // ordered-uint running min
  unsigned int max_ord;          // ordered-uint running max
  int sel_base;                  // first global candidate index of exact window
  unsigned int pad0;
  double sub_scores[NCAND];      // subsample sums, all 80 candidates
  double exact_scores[NEXACT + 1]; // exact sums for window (+1 pad -> 16B align)
  float4 sel[NEXACT];            // per-window-candidate {delta, 1/delta, -zp, 255-zp}
  float4 final_params;
};

__device__ __forceinline__ unsigned int f2o(float f) {
  unsigned int u = __float_as_uint(f);
  return (u & 0x80000000u) ? ~u : (u | 0x80000000u);
}
__device__ __forceinline__ float o2f(unsigned int o) {
  unsigned int u = (o & 0x80000000u) ? (o ^ 0x80000000u) : ~o;
  return __uint_as_float(u);
}

__device__ __forceinline__ float4 cand_params(float xmin, float xmax, int c) {
  float f  = 1.0f - (float)c * 0.01f;          // matches ref f32 arith
  float mn = xmin * f, mx = xmax * f;
  float delta = fmaxf(mx - mn, 1e-8f) / 255.0f;
  float zp = rintf(-mn / delta);               // round-half-even == jnp.round
  return make_float4(delta, 1.0f / delta, -zp, 255.0f - zp);
}

// err^p summand; e==0 -> exp2(-inf) = 0
__device__ __forceinline__ float powp(float x, float4 k) {
  float r = fminf(fmaxf(rintf(x * k.y), k.z), k.w);
  float e = fabsf(fmaf(r, k.x, -x));
  return EXP2F(2.4f * LOG2F(e));
}

__global__ void k_init(WS* ws) {
  int t = threadIdx.x;
  if (t < NCAND) ws->sub_scores[t] = 0.0;
  if (t < NEXACT + 1) ws->exact_scores[t] = 0.0;
  if (t == 0) { ws->min_ord = 0xFFFFFFFFu; ws->max_ord = 0u; }
}

__global__ __launch_bounds__(256) void k_minmax(const float4* __restrict__ x4, int n4, WS* ws) {
  float mn = INFINITY, mx = -INFINITY;
  int idx = blockIdx.x * blockDim.x + threadIdx.x;
  int stride = gridDim.x * blockDim.x;
  for (int i = idx; i < n4; i += stride) {
    float4 v = x4[i];
    mn = fminf(mn, fminf(fminf(v.x, v.y), fminf(v.z, v.w)));
    mx = fmaxf(mx, fmaxf(fmaxf(v.x, v.y), fmaxf(v.z, v.w)));
  }
  #pragma unroll
  for (int off = 32; off; off >>= 1) {
    mn = fminf(mn, __shfl_xor(mn, off));
    mx = fmaxf(mx, __shfl_xor(mx, off));
  }
  __shared__ float smn[4], smx[4];
  int wid = threadIdx.x >> 6;
  if ((threadIdx.x & 63) == 0) { smn[wid] = mn; smx[wid] = mx; }
  __syncthreads();
  if (threadIdx.x == 0) {
    mn = fminf(fminf(smn[0], smn[1]), fminf(smn[2], smn[3]));
    mx = fmaxf(fmaxf(smx[0], smx[1]), fmaxf(smx[2], smx[3]));
    atomicMin(&ws->min_ord, f2o(mn));
    atomicMax(&ws->max_ord, f2o(mx));
  }
}

// Phase 1: all 80 candidates on a 1/16 coalesced subsample (4KB chunk per 64KB).
// 512 blocks x 256 threads x 2 float4 = 262144 float4 = 1.05M elements.
__global__ __launch_bounds__(256) void k_sub(const float4* __restrict__ x4, int n4, WS* ws) {
  __shared__ float4 cc[NCAND];
  if (threadIdx.x < NCAND) {
    float xmin = o2f(ws->min_ord), xmax = o2f(ws->max_ord);
    cc[threadIdx.x] = cand_params(xmin, xmax, threadIdx.x);
  }
  __syncthreads();

  float xv[8];
  #pragma unroll
  for (int j = 0; j < 2; j++) {
    int s = j * (512 * 256) + blockIdx.x * 256 + threadIdx.x; // sample idx
    int d = (s >> 8) * 4096 + (s & 255);                      // data float4 idx
    float4 v = (d < n4) ? x4[d] : make_float4(0.f, 0.f, 0.f, 0.f);
    xv[4 * j + 0] = v.x; xv[4 * j + 1] = v.y;
    xv[4 * j + 2] = v.z; xv[4 * j + 3] = v.w;
  }

  __shared__ float part[4][NCAND];
  int wid = threadIdx.x >> 6, lane = threadIdx.x & 63;

  #pragma unroll 1
  for (int c = 0; c < NCAND; c++) {
    float4 k = cc[c];
    float s0 = 0.f, s1 = 0.f;
    #pragma unroll
    for (int e = 0; e < 8; e += 2) {
      s0 += powp(xv[e], k);
      s1 += powp(xv[e + 1], k);
    }
    float s = s0 + s1;
    #pragma unroll
    for (int off = 32; off; off >>= 1) s += __shfl_xor(s, off);
    if (lane == 0) part[wid][c] = s;
  }
  __syncthreads();
  if (threadIdx.x < NCAND) {
    double tot = (double)part[0][threadIdx.x] + (double)part[1][threadIdx.x]
               + (double)part[2][threadIdx.x] + (double)part[3][threadIdx.x];
    atomicAdd(&ws->sub_scores[threadIdx.x], tot);
  }
}

// Pick window of NEXACT candidates centered on subsample argmin; precompute params.
__global__ void k_select(WS* ws) {
  if (threadIdx.x == 0 && blockIdx.x == 0) {
    double best = ws->sub_scores[0];
    int bi = 0;
    for (int i = 1; i < NCAND; i++) {
      double s = ws->sub_scores[i];
      if (s < best) { best = s; bi = i; }
    }
    int lo = bi - (NEXACT / 2);
    if (lo < 0) lo = 0;
    if (lo > NCAND - NEXACT) lo = NCAND - NEXACT;
    ws->sel_base = lo;
    float xmin = o2f(ws->min_ord), xmax = o2f(ws->max_ord);
    for (int j = 0; j < NEXACT; j++) ws->sel[j] = cand_params(xmin, xmax, lo + j);
  }
}

// Phase 2: exact scores for the NEXACT window over the full tensor.
__global__ __launch_bounds__(256) void k_exact(const float4* __restrict__ x4, int n4, WS* ws) {
  __shared__ float4 cc[NEXACT];
  if (threadIdx.x < NEXACT) cc[threadIdx.x] = ws->sel[threadIdx.x];
  __syncthreads();

  float xv[4 * NPT];
  int base = blockIdx.x * (256 * NPT) + threadIdx.x;
  #pragma unroll
  for (int j = 0; j < NPT; j++) {
    int i = base + j * 256;
    float4 v = (i < n4) ? x4[i] : make_float4(0.f, 0.f, 0.f, 0.f);
    xv[4 * j + 0] = v.x; xv[4 * j + 1] = v.y;
    xv[4 * j + 2] = v.z; xv[4 * j + 3] = v.w;
  }

  __shared__ float part[4][NEXACT];
  int wid = threadIdx.x >> 6, lane = threadIdx.x & 63;

  #pragma unroll 1
  for (int c = 0; c < NEXACT; c++) {
    float4 k = cc[c];
    float s0 = 0.f, s1 = 0.f, s2 = 0.f, s3 = 0.f;
    #pragma unroll
    for (int e = 0; e < 4 * NPT; e += 4) {
      s0 += powp(xv[e], k);
      s1 += powp(xv[e + 1], k);
      s2 += powp(xv[e + 2], k);
      s3 += powp(xv[e + 3], k);
    }
    float s = (s0 + s1) + (s2 + s3);
    #pragma unroll
    for (int off = 32; off; off >>= 1) s += __shfl_xor(s, off);
    if (lane == 0) part[wid][c] = s;
  }
  __syncthreads();
  if (threadIdx.x < NEXACT) {
    double tot = (double)part[0][threadIdx.x] + (double)part[1][threadIdx.x]
               + (double)part[2][threadIdx.x] + (double)part[3][threadIdx.x];
    atomicAdd(&ws->exact_scores[threadIdx.x], tot);
  }
}

__global__ void k_argmin(WS* ws, const float* __restrict__ minbuf, const float* __restrict__ maxbuf) {
  if (threadIdx.x == 0 && blockIdx.x == 0) {
    double best = ws->exact_scores[0];
    int bj = 0;
    for (int j = 1; j < NEXACT; j++) {          // ties -> first (strict <) == smallest global idx
      double s = ws->exact_scores[j];
      if (s < best) { best = s; bj = j; }
    }
    int c = ws->sel_base + bj;
    float factor = 1.0f - (float)c * 0.01f;
    float xmin = o2f(ws->min_ord), xmax = o2f(ws->max_ord);
    float save_min = xmin * factor, save_max = xmax * factor;
    float new_min = minbuf[0] * 0.9f + save_min * 0.1f;
    float new_max = maxbuf[0] * 0.9f + save_max * 0.1f;
    float delta = fmaxf(new_max - new_min, 1e-8f) / 255.0f;
    float zp = rintf(-new_min / delta);
    ws->final_params = make_float4(delta, 1.0f / delta, -zp, 255.0f - zp);
  }
}

__global__ __launch_bounds__(256) void k_quant(const float4* __restrict__ x4, float4* __restrict__ o4,
                                               int n4, const WS* __restrict__ ws) {
  float4 k = ws->final_params;
  int idx = blockIdx.x * blockDim.x + threadIdx.x;
  int stride = gridDim.x * blockDim.x;
  for (int i = idx; i < n4; i += stride) {
    float4 v = x4[i];
    float4 o;
    o.x = fminf(fmaxf(rintf(v.x * k.y), k.z), k.w) * k.x;
    o.y = fminf(fmaxf(rintf(v.y * k.y), k.z), k.w) * k.x;
    o.z = fminf(fmaxf(rintf(v.z * k.y), k.z), k.w) * k.x;
    o.w = fminf(fmaxf(rintf(v.w * k.y), k.z), k.w) * k.x;
    o4[i] = o;
  }
}

extern "C" void kernel_launch(void* const* d_in, const int* in_sizes, int n_in,
                              void* d_out, int out_size, void* d_ws, size_t ws_size,
                              hipStream_t stream) {
  const float* x      = (const float*)d_in[0];
  const float* minbuf = (const float*)d_in[1];
  const float* maxbuf = (const float*)d_in[2];
  float* out = (float*)d_out;
  WS* ws = (WS*)d_ws;
  int n  = in_sizes[0];
  int n4 = n / 4;  // n = 16,777,216 -> divisible

  k_init<<<1, 128, 0, stream>>>(ws);

  int mmBlocks = (n4 + 256 * 8 - 1) / (256 * 8);
  if (mmBlocks > 2048) mmBlocks = 2048;
  k_minmax<<<mmBlocks, 256, 0, stream>>>((const float4*)x, n4, ws);

  k_sub<<<512, 256, 0, stream>>>((const float4*)x, n4, ws);

  k_select<<<1, 64, 0, stream>>>(ws);

  int exBlocks = (n4 + 256 * NPT - 1) / (256 * NPT);  // 2048 for n=16M
  k_exact<<<exBlocks, 256, 0, stream>>>((const float4*)x, n4, ws);

  k_argmin<<<1, 64, 0, stream>>>(ws, minbuf, maxbuf);

  int qBlocks = (n4 + 256 * 4 - 1) / (256 * 4);
  if (qBlocks > 4096) qBlocks = 4096;
  k_quant<<<qBlocks, 256, 0, stream>>>((const float4*)x, (float4*)out, n4, ws);
}